// Round 1
// baseline (531.395 us; speedup 1.0000x reference)
//
#include <hip/hip_runtime.h>
#include <math.h>

// ---------------- constants ----------------
#define BATCH 512
#define DIM 512
#define NCLS 100000
#define S_SCALE 64.0f
#define COS_M 0.8775825618903728f
#define SIN_M 0.479425538604203f
#define TH_C (-0.8775825618903728f)
#define MM_C 0.2397127693021015f
#define CLIP_LO (-1.0f + 1e-7f)
#define CLIP_HI (1.0f - 1e-7f)

typedef __attribute__((ext_vector_type(8))) short bf16x8;
typedef __attribute__((ext_vector_type(4))) float f32x4;

__device__ __forceinline__ unsigned short f2bf_rne(float x) {
    union { float f; unsigned int u; } v;
    v.f = x;
    unsigned int u = v.u;
    u += 0x7fffu + ((u >> 16) & 1u);
    return (unsigned short)(u >> 16);
}

// async global->LDS, 16B per lane; LDS dest = wave-uniform base + lane*16
#define GLD16(gp, lp)                                                          \
    __builtin_amdgcn_global_load_lds(                                          \
        (const __attribute__((address_space(1))) void*)(gp),                   \
        (__attribute__((address_space(3))) void*)(lp), 16, 0, 0)

// ---------------- kernel 1: normalize embeddings -> bf16, zero sumexp -------
__global__ void k_norm_e(const float* __restrict__ e, short* __restrict__ ebf,
                         float* __restrict__ sumexp) {
    int row = blockIdx.x;       // 512 rows
    int tid = threadIdx.x;      // 128 threads, 4 floats each
    const float4* p = (const float4*)(e + (size_t)row * DIM);
    float4 v = p[tid];
    float ss = v.x * v.x + v.y * v.y + v.z * v.z + v.w * v.w;
    for (int m = 1; m < 64; m <<= 1) ss += __shfl_xor(ss, m, 64);
    __shared__ float wss[2];
    int wv = tid >> 6;
    if ((tid & 63) == 0) wss[wv] = ss;
    __syncthreads();
    float tot = wss[0] + wss[1];
    float inv = 1.0f / fmaxf(sqrtf(tot), 1e-12f);
    ushort4 o;
    o.x = f2bf_rne(v.x * inv);
    o.y = f2bf_rne(v.y * inv);
    o.z = f2bf_rne(v.z * inv);
    o.w = f2bf_rne(v.w * inv);
    ((ushort4*)(ebf + (size_t)row * DIM))[tid] = o;
    if (tid == 0) sumexp[row] = 0.0f;
}

// ---------------- kernel 2: normalize weight rows -> bf16 -------------------
__global__ void k_norm_w(const float* __restrict__ w, short* __restrict__ wbf) {
    int wv = threadIdx.x >> 6;
    int lane = threadIdx.x & 63;
    int row = blockIdx.x * 4 + wv;  // 25000 * 4 == 100000 exactly
    const float4* p = (const float4*)(w + (size_t)row * DIM);
    float4 a = p[lane * 2];
    float4 b = p[lane * 2 + 1];
    float ss = a.x * a.x + a.y * a.y + a.z * a.z + a.w * a.w +
               b.x * b.x + b.y * b.y + b.z * b.z + b.w * b.w;
    for (int m = 1; m < 64; m <<= 1) ss += __shfl_xor(ss, m, 64);
    float inv = 1.0f / fmaxf(sqrtf(ss), 1e-12f);
    ushort4 o0, o1;
    o0.x = f2bf_rne(a.x * inv); o0.y = f2bf_rne(a.y * inv);
    o0.z = f2bf_rne(a.z * inv); o0.w = f2bf_rne(a.w * inv);
    o1.x = f2bf_rne(b.x * inv); o1.y = f2bf_rne(b.y * inv);
    o1.z = f2bf_rne(b.z * inv); o1.w = f2bf_rne(b.w * inv);
    ushort4* q = (ushort4*)(wbf + (size_t)row * DIM);
    q[lane * 2] = o0;
    q[lane * 2 + 1] = o1;
}

// ---------------- kernel 3: fused GEMM + arcface margin + sumexp ------------
// grid.x = ceil(NCLS/128) * 4 ; block = 256 (4 waves, 2x2 of 64x64)
__global__ __launch_bounds__(256) void k_gemm(
    const short* __restrict__ ebf, const short* __restrict__ wbf,
    const int* __restrict__ labels, float* __restrict__ sumexp,
    float* __restrict__ phiS) {
    __shared__ short As[128 * 64];
    __shared__ short Bs[128 * 64];
    __shared__ int sLbl[128];

    int bx = blockIdx.x;
    int mb = bx & 3;        // 4 row-blocks of 128
    int nb = bx >> 2;       // 782 col-blocks of 128
    int n0 = nb * 128;

    int tid = threadIdx.x;
    int lane = tid & 63;
    int wv = tid >> 6;      // wave 0..3
    int wm = wv >> 1;       // 0,1 : row half
    int wn = wv & 1;        // 0,1 : col half

    if (tid < 128) sLbl[tid] = labels[mb * 128 + tid];

    f32x4 acc[4][4];
#pragma unroll
    for (int i = 0; i < 4; ++i)
#pragma unroll
        for (int j = 0; j < 4; ++j) acc[i][j] = (f32x4){0.f, 0.f, 0.f, 0.f};

    int lr = lane >> 3;          // 0..7 row within 8-row stripe
    int lc8 = (lane & 7) * 8;    // element col offset within 64
    int quad = lane >> 4;
    int l16 = lane & 15;

    for (int kc = 0; kc < DIM / 64; ++kc) {
        // ---- stage A(128x64) and B(128x64) tiles via async DMA ----
#pragma unroll
        for (int i = 0; i < 4; ++i) {
            int r = wv * 32 + i * 8;  // wave-uniform stripe base
            const short* ga =
                ebf + (size_t)(mb * 128 + r + lr) * DIM + kc * 64 + lc8;
            GLD16(ga, &As[r * 64]);
            int wrow = n0 + r + lr;
            if (wrow > NCLS - 1) wrow = NCLS - 1;
            const short* gb = wbf + (size_t)wrow * DIM + kc * 64 + lc8;
            GLD16(gb, &Bs[r * 64]);
        }
        __syncthreads();
        // ---- compute: 2 k-steps of 32 ----
#pragma unroll
        for (int ks = 0; ks < 2; ++ks) {
            bf16x8 af[4], bf[4];
#pragma unroll
            for (int t = 0; t < 4; ++t) {
                int mrow = wm * 64 + t * 16 + l16;
                af[t] = *(const bf16x8*)&As[mrow * 64 + ks * 32 + quad * 8];
            }
#pragma unroll
            for (int t = 0; t < 4; ++t) {
                int nrow = wn * 64 + t * 16 + l16;
                bf[t] = *(const bf16x8*)&Bs[nrow * 64 + ks * 32 + quad * 8];
            }
#pragma unroll
            for (int tm = 0; tm < 4; ++tm)
#pragma unroll
                for (int tn = 0; tn < 4; ++tn)
                    acc[tm][tn] = __builtin_amdgcn_mfma_f32_16x16x32_bf16(
                        af[tm], bf[tn], acc[tm][tn], 0, 0, 0);
        }
        __syncthreads();
    }

    // ---- epilogue: clip, margin on label col, exp, per-row reduce ----
    float rowsum[16];  // [tm*4 + r]
#pragma unroll
    for (int i = 0; i < 16; ++i) rowsum[i] = 0.0f;

#pragma unroll
    for (int tm = 0; tm < 4; ++tm) {
#pragma unroll
        for (int r = 0; r < 4; ++r) {
            int m_local = wm * 64 + tm * 16 + quad * 4 + r;
            int lbl = sLbl[m_local];
            float rs = 0.0f;
#pragma unroll
            for (int tn = 0; tn < 4; ++tn) {
                float c = acc[tm][tn][r];
                c = fminf(fmaxf(c, CLIP_LO), CLIP_HI);
                int col = n0 + wn * 64 + tn * 16 + l16;
                float t = c;
                if (col == lbl) {
                    float sn = sqrtf(fmaxf(1.0f - c * c, 0.0f));
                    float ph = c * COS_M - sn * SIN_M;
                    ph = (c > TH_C) ? ph : (c - MM_C);
                    t = ph;
                    phiS[mb * 128 + m_local] = S_SCALE * ph;
                }
                float ex = (col < NCLS) ? __expf(S_SCALE * t - 64.0f) : 0.0f;
                rs += ex;
            }
            rowsum[tm * 4 + r] = rs;
        }
    }
    // butterfly-reduce each (tm,r) over the 16 lanes sharing the row,
    // then lane (l16 == idx) issues the single atomic for that row.
#pragma unroll
    for (int idx = 0; idx < 16; ++idx) {
        float v = rowsum[idx];
        v += __shfl_xor(v, 1, 64);
        v += __shfl_xor(v, 2, 64);
        v += __shfl_xor(v, 4, 64);
        v += __shfl_xor(v, 8, 64);
        if (l16 == idx) {
            int tm = idx >> 2, r = idx & 3;
            int m_local = wm * 64 + tm * 16 + quad * 4 + r;
            atomicAdd(&sumexp[mb * 128 + m_local], v);
        }
    }
}

// ---------------- kernel 4: nll + mean ----------------
__global__ void k_final(const float* __restrict__ sumexp,
                        const float* __restrict__ phiS,
                        float* __restrict__ out) {
    int tid = threadIdx.x;  // 512
    float nll = 64.0f + logf(sumexp[tid]) - phiS[tid];
    for (int m = 1; m < 64; m <<= 1) nll += __shfl_xor(nll, m, 64);
    __shared__ float ws[8];
    int wv = tid >> 6;
    if ((tid & 63) == 0) ws[wv] = nll;
    __syncthreads();
    if (tid == 0) {
        float s = 0.0f;
        for (int j = 0; j < 8; ++j) s += ws[j];
        out[0] = s / (float)BATCH;
    }
}

// ---------------- launch ----------------
extern "C" void kernel_launch(void* const* d_in, const int* in_sizes, int n_in,
                              void* d_out, int out_size, void* d_ws,
                              size_t ws_size, hipStream_t stream) {
    const float* emb = (const float*)d_in[0];
    const float* wgt = (const float*)d_in[1];
    const int* lbl = (const int*)d_in[2];

    char* ws = (char*)d_ws;
    short* wbf = (short*)ws;                              // 102,400,000 B
    short* ebf = (short*)(ws + 102400000);                // 524,288 B
    float* sumexp = (float*)(ws + 102924288);             // 2048 B
    float* phiS = (float*)(ws + 102926336);               // 2048 B

    k_norm_e<<<dim3(BATCH), dim3(128), 0, stream>>>(emb, ebf, sumexp);
    k_norm_w<<<dim3(NCLS / 4), dim3(256), 0, stream>>>(wgt, wbf);
    int nblocks = ((NCLS + 127) / 128) * 4;  // 782 * 4 = 3128
    k_gemm<<<dim3(nblocks), dim3(256), 0, stream>>>(ebf, wbf, lbl, sumexp,
                                                    phiS);
    k_final<<<dim3(1), dim3(512), 0, stream>>>(sumexp, phiS, (float*)d_out);
}